// Round 7
// baseline (1084.548 us; speedup 1.0000x reference)
//
#include <hip/hip_runtime.h>

// ============ DIAGNOSTIC ROUND: k_fused x8, k_tower x24 amplification ======
// Identical algorithm to R6 (50.9us). Amplification surfaces our kernels in
// the rocprof top-5 (past the harness's ~150us fill dispatches) to get
// per-kernel dur + MfmaUtil/VALUBusy/Occupancy/FETCH_SIZE for the first time.

#define B_SZ  16384
#define F_SZ  20
#define V_SZ  100000
#define E_SZ  32
#define DBOT  640
#define D1    512
#define D2    256
#define T1D   128
#define T2D   64
#define NDOM  4

#define AMP_FUSED 8
#define AMP_TOWER 24

typedef __bf16 bf16x8 __attribute__((ext_vector_type(8)));
typedef float  f32x4  __attribute__((ext_vector_type(4)));

#define MFMA(a, b, c) __builtin_amdgcn_mfma_f32_16x16x32_bf16((a), (b), (c), 0, 0, 0)

// ---------------------------------------------------------------------------
// Prep: pack all weights into MFMA-fragment order bf16 (unchanged from R3/R6).
// ---------------------------------------------------------------------------
__global__ __launch_bounds__(256) void k_prep(const float* __restrict__ W1,
                                              const float* __restrict__ W2,
                                              const float* __restrict__ TW1,
                                              const float* __restrict__ TW2,
                                              __bf16* __restrict__ W1P,
                                              __bf16* __restrict__ W2P,
                                              __bf16* __restrict__ TW1P,
                                              __bf16* __restrict__ TW2P,
                                              int* __restrict__ cnt) {
  int bid = blockIdx.x, tid = threadIdx.x;
  const float* src; __bf16* dst; int n, k, N;
  if (bid < 160) {
    long g = (long)bid * 256 + tid;
    int lane = g & 63; int kkg = (int)((g >> 6) % 20); int ntile = (int)(g / 1280);
    n = ntile * 16 + (lane & 15); k = kkg * 32 + ((lane >> 4) << 3);
    src = W1; N = D1; dst = W1P + g * 8;
  } else if (bid < 224) {
    long g = (long)(bid - 160) * 256 + tid;
    int lane = g & 63; int kkg = (int)((g >> 6) & 15); int ntile = (int)(g >> 10);
    n = ntile * 16 + (lane & 15); k = kkg * 32 + ((lane >> 4) << 3);
    src = W2; N = D2; dst = W2P + g * 8;
  } else if (bid < 288) {
    long g = (long)(bid - 224) * 256 + tid;
    int d = (int)(g >> 12); long r = g & 4095;
    int lane = r & 63; int kkg = (int)((r >> 6) & 7); int ntile = (int)(r >> 9);
    n = ntile * 16 + (lane & 15); k = kkg * 32 + ((lane >> 4) << 3);
    src = TW1 + (long)d * D2 * T1D; N = T1D;
    dst = TW1P + ((long)(d * 64 + ntile * 8 + kkg) * 64 + lane) * 8;
  } else if (bid < 304) {
    long g = (long)(bid - 288) * 256 + tid;
    int d = (int)(g >> 10); long r = g & 1023;
    int lane = r & 63; int kkg = (int)((r >> 6) & 3); int ntile = (int)(r >> 8);
    n = ntile * 16 + (lane & 15); k = kkg * 32 + ((lane >> 4) << 3);
    src = TW2 + (long)d * T1D * T2D; N = T2D;
    dst = TW2P + ((long)(d * 16 + ntile * 4 + kkg) * 64 + lane) * 8;
  } else {
    if (tid < NDOM) cnt[tid] = 0;
    return;
  }
  bf16x8 o;
#pragma unroll
  for (int e = 0; e < 8; ++e) o[e] = (__bf16)src[(long)(k + e) * N + n];
  *(bf16x8*)dst = o;
}

// ---------------------------------------------------------------------------
// Fused (R6 algorithm, body amplified x8; partition only on it==0).
// ---------------------------------------------------------------------------
__global__ __launch_bounds__(512, 2) void k_fused(const int* __restrict__ fids,
                                                  const int* __restrict__ dom,
                                                  const float* __restrict__ emb,
                                                  const __bf16* __restrict__ W1P,
                                                  const float* __restrict__ b1,
                                                  const __bf16* __restrict__ W2P,
                                                  const float* __restrict__ b2,
                                                  __bf16* __restrict__ h2,
                                                  int* __restrict__ cnt,
                                                  int* __restrict__ lists) {
  __shared__ int    ids_lds[64 * F_SZ];
  __shared__ __bf16 sA[2][64 * 64];
  __shared__ __bf16 h1[64 * D1];

  int bid = blockIdx.x, tid = threadIdx.x;
  int lane = tid & 63, w = tid >> 6;
  int lrow = lane & 15, kq = lane >> 4;
  int m0 = bid * 64;

#pragma unroll 1
  for (int it = 0; it < AMP_FUSED; ++it) {
    // ---- domain partition (once; cnt/lists identical across replays' prep-zero) ----
    if (it == 0 && bid < 64 && tid < 256) {
      int i = bid * 256 + tid;
      int d = dom[i];
      int pl = tid & 63;
#pragma unroll
      for (int dd = 0; dd < NDOM; ++dd) {
        unsigned long long md = __ballot(d == dd);
        if (d == dd) {
          int myoff = __popcll(md & ((1ull << pl) - 1ull));
          int leader = __ffsll((long long)md) - 1;
          int base = 0;
          if (pl == leader) base = atomicAdd(&cnt[dd], __popcll(md));
          base = __shfl(base, leader);
          lists[dd * B_SZ + base + myoff] = i;
        }
      }
    }

    // ---- stage feature ids (same values every iteration: benign race) ----
    for (int i = tid; i < 64 * F_SZ; i += 512) ids_lds[i] = fids[m0 * F_SZ + i];
    __syncthreads();

    int srow = tid >> 3, sc = tid & 7;
    int sbyte = srow * 128 + ((sc ^ (srow & 7)) << 4);
    int fsub = sc >> 2, esub = (sc & 3) << 3;

    float4 g0a, g1a, g0b, g1b;
    {
      int id = ids_lds[srow * F_SZ + fsub];
      const float* p = emb + ((long)fsub * V_SZ + id) * E_SZ + esub;
      g0a = *(const float4*)p; g1a = *(const float4*)(p + 4);
    }
    {
      int id = ids_lds[srow * F_SZ + 2 + fsub];
      const float* p = emb + ((long)(2 + fsub) * V_SZ + id) * E_SZ + esub;
      g0b = *(const float4*)p; g1b = *(const float4*)(p + 4);
    }
    bf16x8 bfA[8], bfB[8];
#pragma unroll
    for (int ni = 0; ni < 4; ++ni)
#pragma unroll
      for (int kk = 0; kk < 2; ++kk)
        bfA[ni * 2 + kk] = *(const bf16x8*)(W1P +
            ((long)((w * 4 + ni) * 20 + kk) * 64 + lane) * 8);

    f32x4 acc[4][4] = {};

#define BODY(S, G0, G1, BC, BN)                                              \
    {                                                                        \
      bf16x8 o;                                                              \
      o[0]=(__bf16)G0.x; o[1]=(__bf16)G0.y; o[2]=(__bf16)G0.z; o[3]=(__bf16)G0.w; \
      o[4]=(__bf16)G1.x; o[5]=(__bf16)G1.y; o[6]=(__bf16)G1.z; o[7]=(__bf16)G1.w; \
      *(bf16x8*)((char*)sA + ((S) & 1) * 8192 + sbyte) = o;                  \
      asm volatile("s_waitcnt lgkmcnt(0)" ::: "memory");                     \
      __builtin_amdgcn_s_barrier();                                          \
      __builtin_amdgcn_sched_barrier(0);                                     \
      const char* sAb = (const char*)sA + ((S) & 1) * 8192;                  \
      bf16x8 af[2][4];                                                       \
      _Pragma("unroll")                                                      \
      for (int kk = 0; kk < 2; ++kk)                                         \
        _Pragma("unroll")                                                    \
        for (int mi = 0; mi < 4; ++mi) {                                     \
          int byte = ((mi * 16 + lrow) * 128 + (kk * 32 + kq * 8) * 2) ^ ((lrow & 7) << 4); \
          af[kk][mi] = *(const bf16x8*)(sAb + byte);                         \
        }                                                                    \
      _Pragma("unroll")                                                      \
      for (int kk = 0; kk < 2; ++kk)                                         \
        _Pragma("unroll")                                                    \
        for (int ni = 0; ni < 4; ++ni)                                       \
          _Pragma("unroll")                                                  \
          for (int mi = 0; mi < 4; ++mi)                                     \
            acc[mi][ni] = MFMA(af[kk][mi], BC[ni * 2 + kk], acc[mi][ni]);    \
      if ((S) + 1 < 10) {                                                    \
        _Pragma("unroll")                                                    \
        for (int ni = 0; ni < 4; ++ni)                                       \
          _Pragma("unroll")                                                  \
          for (int kk = 0; kk < 2; ++kk)                                     \
            BN[ni * 2 + kk] = *(const bf16x8*)(W1P +                         \
                ((long)((w * 4 + ni) * 20 + ((S) + 1) * 2 + kk) * 64 + lane) * 8); \
      }                                                                      \
      if ((S) + 2 < 10) {                                                    \
        int f = 2 * ((S) + 2) + fsub;                                        \
        int id = ids_lds[srow * F_SZ + f];                                   \
        const float* p = emb + ((long)f * V_SZ + id) * E_SZ + esub;          \
        G0 = *(const float4*)p; G1 = *(const float4*)(p + 4);                \
      }                                                                      \
    }

    BODY(0, g0a, g1a, bfA, bfB)
    BODY(1, g0b, g1b, bfB, bfA)
    BODY(2, g0a, g1a, bfA, bfB)
    BODY(3, g0b, g1b, bfB, bfA)
    BODY(4, g0a, g1a, bfA, bfB)
    BODY(5, g0b, g1b, bfB, bfA)
    BODY(6, g0a, g1a, bfA, bfB)
    BODY(7, g0b, g1b, bfB, bfA)
    BODY(8, g0a, g1a, bfA, bfB)
    BODY(9, g0b, g1b, bfB, bfA)
#undef BODY

    // h1 = relu(. + b1) -> LDS
#pragma unroll
    for (int ni = 0; ni < 4; ++ni) {
      int col = w * 64 + ni * 16 + lrow;
      float bv = b1[col];
#pragma unroll
      for (int mi = 0; mi < 4; ++mi) {
#pragma unroll
        for (int r = 0; r < 4; ++r) {
          int row = mi * 16 + kq * 4 + r;
          float v = acc[mi][ni][r] + bv;
          v = v > 0.f ? v : 0.f;
          int byte = (row * 1024 + col * 2) ^ ((row & 7) << 4);
          *(__bf16*)((char*)h1 + byte) = (__bf16)v;
        }
      }
    }
    __syncthreads();

    // GEMM2
    f32x4 acc2[4][2] = {};
    for (int kkg = 0; kkg < 16; ++kkg) {
      bf16x8 a2[4];
#pragma unroll
      for (int mi = 0; mi < 4; ++mi) {
        int byte = ((mi * 16 + lrow) * 1024 + kkg * 64 + kq * 16) ^ ((lrow & 7) << 4);
        a2[mi] = *(const bf16x8*)((const char*)h1 + byte);
      }
#pragma unroll
      for (int ni = 0; ni < 2; ++ni) {
        bf16x8 bfr = *(const bf16x8*)(W2P +
            ((long)((w * 2 + ni) * 16 + kkg) * 64 + lane) * 8);
#pragma unroll
        for (int mi = 0; mi < 4; ++mi)
          acc2[mi][ni] = MFMA(a2[mi], bfr, acc2[mi][ni]);
      }
    }

    // h2 store
#pragma unroll
    for (int ni = 0; ni < 2; ++ni) {
      int col = w * 32 + ni * 16 + lrow;
      float bv = b2[col];
#pragma unroll
      for (int mi = 0; mi < 4; ++mi) {
#pragma unroll
        for (int r = 0; r < 4; ++r) {
          long row = m0 + mi * 16 + kq * 4 + r;
          float v = acc2[mi][ni][r] + bv;
          v = v > 0.f ? v : 0.f;
          h2[row * D2 + col] = (__bf16)v;
        }
      }
    }
    __syncthreads();   // keep iterations cleanly separated
  }
}

// ---------------------------------------------------------------------------
// Tower (R6 algorithm, amplified x24).
// ---------------------------------------------------------------------------
__global__ __launch_bounds__(256) void k_tower(const __bf16* __restrict__ h2,
                                               const __bf16* __restrict__ TW1P,
                                               const __bf16* __restrict__ TW2P,
                                               const float* __restrict__ Tb1,
                                               const float* __restrict__ Tb2,
                                               const float* __restrict__ TW3,
                                               const float* __restrict__ Tb3,
                                               const int* __restrict__ cnt,
                                               const int* __restrict__ lists,
                                               float* __restrict__ out) {
  __shared__ __bf16 t_lds[4][16 * 128];
  int d  = blockIdx.y;
  int nc = cnt[d];
  int base = blockIdx.x * 64;

  int tid  = threadIdx.x;
  int lane = tid & 63;
  int w    = tid >> 6;
  int row  = lane & 15;
  int kq   = lane >> 4;

#pragma unroll 1
  for (int it = 0; it < AMP_TOWER; ++it) {
    if (base >= nc) continue;
    int slot = base + w * 16 + row;
    bool valid = slot < nc;
    int m0r = lists[d * B_SZ + (valid ? slot : 0)];

    bf16x8 a1[8];
#pragma unroll
    for (int kk = 0; kk < 8; ++kk)
      a1[kk] = *(const bf16x8*)(h2 + (long)m0r * D2 + kk * 32 + kq * 8);

    f32x4 acc1[8] = {};
#pragma unroll
    for (int kk = 0; kk < 8; ++kk) {
#pragma unroll
      for (int ni = 0; ni < 8; ++ni) {
        bf16x8 b = *(const bf16x8*)(TW1P +
            ((long)(d * 64 + ni * 8 + kk) * 64 + lane) * 8);
        acc1[ni] = MFMA(a1[kk], b, acc1[ni]);
      }
    }
#pragma unroll
    for (int ni = 0; ni < 8; ++ni) {
      float bv = Tb1[d * T1D + ni * 16 + row];
#pragma unroll
      for (int r = 0; r < 4; ++r) {
        float v = acc1[ni][r] + bv;
        v = v > 0.f ? v : 0.f;
        t_lds[w][(kq * 4 + r) * 128 + ni * 16 + row] = (__bf16)v;
      }
    }
    asm volatile("s_waitcnt lgkmcnt(0)" ::: "memory");

    bf16x8 a2[4];
#pragma unroll
    for (int kk = 0; kk < 4; ++kk)
      a2[kk] = *(const bf16x8*)(&t_lds[w][row * 128 + kk * 32 + kq * 8]);
    f32x4 acc2[4] = {};
#pragma unroll
    for (int kk = 0; kk < 4; ++kk) {
#pragma unroll
      for (int ni = 0; ni < 4; ++ni) {
        bf16x8 b = *(const bf16x8*)(TW2P +
            ((long)(d * 16 + ni * 4 + kk) * 64 + lane) * 8);
        acc2[ni] = MFMA(a2[kk], b, acc2[ni]);
      }
    }
    asm volatile("s_waitcnt lgkmcnt(0)" ::: "memory");
#pragma unroll
    for (int ni = 0; ni < 4; ++ni) {
      float bv = Tb2[d * T2D + ni * 16 + row];
#pragma unroll
      for (int r = 0; r < 4; ++r) {
        float v = acc2[ni][r] + bv;
        v = v > 0.f ? v : 0.f;
        t_lds[w][(kq * 4 + r) * 64 + ni * 16 + row] = (__bf16)v;
      }
    }
    asm volatile("s_waitcnt lgkmcnt(0)" ::: "memory");

    float s = 0.f;
#pragma unroll
    for (int j = 0; j < 16; ++j)
      s += (float)t_lds[w][row * 64 + kq * 16 + j] * TW3[d * T2D + kq * 16 + j];
    s += __shfl_xor(s, 16);
    s += __shfl_xor(s, 32);
    s += Tb3[d];
    if (valid && kq == 0)
      out[m0r] = 1.0f / (1.0f + expf(-s));
  }
}

// ---------------------------------------------------------------------------
extern "C" void kernel_launch(void* const* d_in, const int* in_sizes, int n_in,
                              void* d_out, int out_size, void* d_ws, size_t ws_size,
                              hipStream_t stream) {
  const int*   fids = (const int*)d_in[0];
  const int*   dom  = (const int*)d_in[1];
  const float* emb  = (const float*)d_in[2];
  const float* W1   = (const float*)d_in[3];
  const float* b1   = (const float*)d_in[4];
  const float* W2   = (const float*)d_in[5];
  const float* b2   = (const float*)d_in[6];
  const float* TW1  = (const float*)d_in[7];
  const float* Tb1  = (const float*)d_in[8];
  const float* TW2  = (const float*)d_in[9];
  const float* Tb2  = (const float*)d_in[10];
  const float* TW3  = (const float*)d_in[11];
  const float* Tb3  = (const float*)d_in[12];
  float* out = (float*)d_out;

  char* ws = (char*)d_ws;
  __bf16* W1P   = (__bf16*)(ws);
  __bf16* W2P   = (__bf16*)(ws + 655360);
  __bf16* TW1P  = (__bf16*)(ws + 917504);
  __bf16* TW2P  = (__bf16*)(ws + 1179648);
  __bf16* h2    = (__bf16*)(ws + 1245184);
  int*    lists = (int*)(ws + 9633792);
  int*    cnt   = (int*)(ws + 9895936);

  k_prep<<<305, 256, 0, stream>>>(W1, W2, TW1, TW2, W1P, W2P, TW1P, TW2P, cnt);
  k_fused<<<256, 512, 0, stream>>>(fids, dom, emb, W1P, b1, W2P, b2, h2,
                                   cnt, lists);
  k_tower<<<dim3(80, NDOM), 256, 0, stream>>>(h2, TW1P, TW2P, Tb1, Tb2,
                                              TW3, Tb3, cnt, lists, out);
}

// Round 8
// 51.328 us; speedup vs baseline: 21.1298x; 21.1298x over previous
//
#include <hip/hip_runtime.h>

#define B_SZ  16384
#define F_SZ  20
#define V_SZ  100000
#define E_SZ  32
#define DBOT  640
#define D1    512
#define D2    256
#define T1D   128
#define T2D   64
#define NDOM  4

typedef __bf16 bf16x8 __attribute__((ext_vector_type(8)));
typedef float  f32x4  __attribute__((ext_vector_type(4)));

#define MFMA(a, b, c) __builtin_amdgcn_mfma_f32_16x16x32_bf16((a), (b), (c), 0, 0, 0)

// ---------------------------------------------------------------------------
// Prep: pack all weights into MFMA-fragment order bf16 (unchanged from R3/R6).
// ---------------------------------------------------------------------------
__global__ __launch_bounds__(256) void k_prep(const float* __restrict__ W1,
                                              const float* __restrict__ W2,
                                              const float* __restrict__ TW1,
                                              const float* __restrict__ TW2,
                                              __bf16* __restrict__ W1P,
                                              __bf16* __restrict__ W2P,
                                              __bf16* __restrict__ TW1P,
                                              __bf16* __restrict__ TW2P,
                                              int* __restrict__ cnt) {
  int bid = blockIdx.x, tid = threadIdx.x;
  const float* src; __bf16* dst; int n, k, N;
  if (bid < 160) {
    long g = (long)bid * 256 + tid;
    int lane = g & 63; int kkg = (int)((g >> 6) % 20); int ntile = (int)(g / 1280);
    n = ntile * 16 + (lane & 15); k = kkg * 32 + ((lane >> 4) << 3);
    src = W1; N = D1; dst = W1P + g * 8;
  } else if (bid < 224) {
    long g = (long)(bid - 160) * 256 + tid;
    int lane = g & 63; int kkg = (int)((g >> 6) & 15); int ntile = (int)(g >> 10);
    n = ntile * 16 + (lane & 15); k = kkg * 32 + ((lane >> 4) << 3);
    src = W2; N = D2; dst = W2P + g * 8;
  } else if (bid < 288) {
    long g = (long)(bid - 224) * 256 + tid;
    int d = (int)(g >> 12); long r = g & 4095;
    int lane = r & 63; int kkg = (int)((r >> 6) & 7); int ntile = (int)(r >> 9);
    n = ntile * 16 + (lane & 15); k = kkg * 32 + ((lane >> 4) << 3);
    src = TW1 + (long)d * D2 * T1D; N = T1D;
    dst = TW1P + ((long)(d * 64 + ntile * 8 + kkg) * 64 + lane) * 8;
  } else if (bid < 304) {
    long g = (long)(bid - 288) * 256 + tid;
    int d = (int)(g >> 10); long r = g & 1023;
    int lane = r & 63; int kkg = (int)((r >> 6) & 3); int ntile = (int)(r >> 8);
    n = ntile * 16 + (lane & 15); k = kkg * 32 + ((lane >> 4) << 3);
    src = TW2 + (long)d * T1D * T2D; N = T2D;
    dst = TW2P + ((long)(d * 16 + ntile * 4 + kkg) * 64 + lane) * 8;
  } else {
    if (tid < NDOM) cnt[tid] = 0;
    return;
  }
  bf16x8 o;
#pragma unroll
  for (int e = 0; e < 8; ++e) o[e] = (__bf16)src[(long)(k + e) * N + n];
  *(bf16x8*)dst = o;
}

// ---------------------------------------------------------------------------
// Fused: gather + GEMM1 + GEMM2 per 64-row panel.
// R8 changes vs R6: (1) __launch_bounds__(512) -- no min-waves clause; the
// old (512,2) capped VGPR at 128 while the hot loop holds ~200 live regs
// (acc 64 + B-frag dbuf 64 + gathers + af) -> scratch spills were the
// latency the idle pipes waited on (R7 diagnostic: VGPR_Count=128, FETCH
// 114MB/iter vs 42 ideal, MfmaUtil 6%).  LDS (87KB) already limits to
// 1 block/CU = 2 waves/SIMD, which admits 256 VGPR -- occupancy unchanged.
// (2) gather prefetch deepened 2 -> 3 (sets A/B/C): commit(s) waits a
// random-row load issued ~3 steps (~1000cy) earlier >= HBM latency.
// ---------------------------------------------------------------------------
__global__ __launch_bounds__(512) void k_fused(const int* __restrict__ fids,
                                               const int* __restrict__ dom,
                                               const float* __restrict__ emb,
                                               const __bf16* __restrict__ W1P,
                                               const float* __restrict__ b1,
                                               const __bf16* __restrict__ W2P,
                                               const float* __restrict__ b2,
                                               __bf16* __restrict__ h2,
                                               int* __restrict__ cnt,
                                               int* __restrict__ lists) {
  __shared__ int    ids_lds[64 * F_SZ];
  __shared__ __bf16 sA[2][64 * 64];
  __shared__ __bf16 h1[64 * D1];

  int bid = blockIdx.x, tid = threadIdx.x;
  int lane = tid & 63, w = tid >> 6;
  int lrow = lane & 15, kq = lane >> 4;
  int m0 = bid * 64;

  // ---- domain partition (blocks 0-63, first 4 waves) ----
  if (bid < 64 && tid < 256) {
    int i = bid * 256 + tid;
    int d = dom[i];
    int pl = tid & 63;
#pragma unroll
    for (int dd = 0; dd < NDOM; ++dd) {
      unsigned long long md = __ballot(d == dd);
      if (d == dd) {
        int myoff = __popcll(md & ((1ull << pl) - 1ull));
        int leader = __ffsll((long long)md) - 1;
        int base = 0;
        if (pl == leader) base = atomicAdd(&cnt[dd], __popcll(md));
        base = __shfl(base, leader);
        lists[dd * B_SZ + base + myoff] = i;
      }
    }
  }

  // ---- stage feature ids ----
  for (int i = tid; i < 64 * F_SZ; i += 512) ids_lds[i] = fids[m0 * F_SZ + i];
  __syncthreads();

  // staging: thread -> (row = tid>>3, 16B chunk sc = tid&7); chunk covers
  // feature 2s+(sc>>2), elems (sc&3)*8.  LDS dest XOR-swizzled by row&7.
  int srow = tid >> 3, sc = tid & 7;
  int sbyte = srow * 128 + ((sc ^ (srow & 7)) << 4);
  int fsub = sc >> 2, esub = (sc & 3) << 3;

  // prologue: 3-deep gather (steps 0,1,2); B-frags for step 0
  float4 g0a, g1a, g0b, g1b, g0c, g1c;
  {
    int id = ids_lds[srow * F_SZ + fsub];
    const float* p = emb + ((long)fsub * V_SZ + id) * E_SZ + esub;
    g0a = *(const float4*)p; g1a = *(const float4*)(p + 4);
  }
  {
    int id = ids_lds[srow * F_SZ + 2 + fsub];
    const float* p = emb + ((long)(2 + fsub) * V_SZ + id) * E_SZ + esub;
    g0b = *(const float4*)p; g1b = *(const float4*)(p + 4);
  }
  {
    int id = ids_lds[srow * F_SZ + 4 + fsub];
    const float* p = emb + ((long)(4 + fsub) * V_SZ + id) * E_SZ + esub;
    g0c = *(const float4*)p; g1c = *(const float4*)(p + 4);
  }
  bf16x8 bfA[8], bfB[8];
#pragma unroll
  for (int ni = 0; ni < 4; ++ni)
#pragma unroll
    for (int kk = 0; kk < 2; ++kk)
      bfA[ni * 2 + kk] = *(const bf16x8*)(W1P +
          ((long)((w * 4 + ni) * 20 + kk) * 64 + lane) * 8);

  f32x4 acc[4][4] = {};

#define BODY(S, G0, G1, BC, BN)                                              \
    {                                                                        \
      bf16x8 o;                                                              \
      o[0]=(__bf16)G0.x; o[1]=(__bf16)G0.y; o[2]=(__bf16)G0.z; o[3]=(__bf16)G0.w; \
      o[4]=(__bf16)G1.x; o[5]=(__bf16)G1.y; o[6]=(__bf16)G1.z; o[7]=(__bf16)G1.w; \
      *(bf16x8*)((char*)sA + ((S) & 1) * 8192 + sbyte) = o;                  \
      asm volatile("s_waitcnt lgkmcnt(0)" ::: "memory");                     \
      __builtin_amdgcn_s_barrier();                                          \
      __builtin_amdgcn_sched_barrier(0);                                     \
      const char* sAb = (const char*)sA + ((S) & 1) * 8192;                  \
      bf16x8 af[2][4];                                                       \
      _Pragma("unroll")                                                      \
      for (int kk = 0; kk < 2; ++kk)                                         \
        _Pragma("unroll")                                                    \
        for (int mi = 0; mi < 4; ++mi) {                                     \
          int byte = ((mi * 16 + lrow) * 128 + (kk * 32 + kq * 8) * 2) ^ ((lrow & 7) << 4); \
          af[kk][mi] = *(const bf16x8*)(sAb + byte);                         \
        }                                                                    \
      _Pragma("unroll")                                                      \
      for (int kk = 0; kk < 2; ++kk)                                         \
        _Pragma("unroll")                                                    \
        for (int ni = 0; ni < 4; ++ni)                                       \
          _Pragma("unroll")                                                  \
          for (int mi = 0; mi < 4; ++mi)                                     \
            acc[mi][ni] = MFMA(af[kk][mi], BC[ni * 2 + kk], acc[mi][ni]);    \
      if ((S) + 1 < 10) {  /* prefetch next step's B-frags */                \
        _Pragma("unroll")                                                    \
        for (int ni = 0; ni < 4; ++ni)                                       \
          _Pragma("unroll")                                                  \
          for (int kk = 0; kk < 2; ++kk)                                     \
            BN[ni * 2 + kk] = *(const bf16x8*)(W1P +                         \
                ((long)((w * 4 + ni) * 20 + ((S) + 1) * 2 + kk) * 64 + lane) * 8); \
      }                                                                      \
      if ((S) + 3 < 10) {  /* issue gathers for step S+3 (youngest vmem) */  \
        int f = 2 * ((S) + 3) + fsub;                                        \
        int id = ids_lds[srow * F_SZ + f];                                   \
        const float* p = emb + ((long)f * V_SZ + id) * E_SZ + esub;          \
        G0 = *(const float4*)p; G1 = *(const float4*)(p + 4);                \
      }                                                                      \
    }

  BODY(0, g0a, g1a, bfA, bfB)
  BODY(1, g0b, g1b, bfB, bfA)
  BODY(2, g0c, g1c, bfA, bfB)
  BODY(3, g0a, g1a, bfB, bfA)
  BODY(4, g0b, g1b, bfA, bfB)
  BODY(5, g0c, g1c, bfB, bfA)
  BODY(6, g0a, g1a, bfA, bfB)
  BODY(7, g0b, g1b, bfB, bfA)
  BODY(8, g0c, g1c, bfA, bfB)
  BODY(9, g0a, g1a, bfB, bfA)
#undef BODY

  // ---- h1 = relu(. + b1) -> LDS (XOR-swizzled rows, 1024B stride) ----
#pragma unroll
  for (int ni = 0; ni < 4; ++ni) {
    int col = w * 64 + ni * 16 + lrow;
    float bv = b1[col];
#pragma unroll
    for (int mi = 0; mi < 4; ++mi) {
#pragma unroll
      for (int r = 0; r < 4; ++r) {
        int row = mi * 16 + kq * 4 + r;
        float v = acc[mi][ni][r] + bv;
        v = v > 0.f ? v : 0.f;
        int byte = (row * 1024 + col * 2) ^ ((row & 7) << 4);
        *(__bf16*)((char*)h1 + byte) = (__bf16)v;
      }
    }
  }
  __syncthreads();

  // ---- GEMM2: h2 = relu(h1 @ W2 + b2), K=512 (16 ksteps) ----
  f32x4 acc2[4][2] = {};
  for (int kkg = 0; kkg < 16; ++kkg) {
    bf16x8 a2[4];
#pragma unroll
    for (int mi = 0; mi < 4; ++mi) {
      int byte = ((mi * 16 + lrow) * 1024 + kkg * 64 + kq * 16) ^ ((lrow & 7) << 4);
      a2[mi] = *(const bf16x8*)((const char*)h1 + byte);
    }
#pragma unroll
    for (int ni = 0; ni < 2; ++ni) {
      bf16x8 bfr = *(const bf16x8*)(W2P +
          ((long)((w * 2 + ni) * 16 + kkg) * 64 + lane) * 8);
#pragma unroll
      for (int mi = 0; mi < 4; ++mi)
        acc2[mi][ni] = MFMA(a2[mi], bfr, acc2[mi][ni]);
    }
  }

  // ---- h2 store (bf16, bias+relu) ----
#pragma unroll
  for (int ni = 0; ni < 2; ++ni) {
    int col = w * 32 + ni * 16 + lrow;
    float bv = b2[col];
#pragma unroll
    for (int mi = 0; mi < 4; ++mi) {
#pragma unroll
      for (int r = 0; r < 4; ++r) {
        long row = m0 + mi * 16 + kq * 4 + r;
        float v = acc2[mi][ni][r] + bv;
        v = v > 0.f ? v : 0.f;
        h2[row * D2 + col] = (__bf16)v;
      }
    }
  }
}

// ---------------------------------------------------------------------------
// Tower (domain-partitioned): unchanged from R3/R6.
// ---------------------------------------------------------------------------
__global__ __launch_bounds__(256) void k_tower(const __bf16* __restrict__ h2,
                                               const __bf16* __restrict__ TW1P,
                                               const __bf16* __restrict__ TW2P,
                                               const float* __restrict__ Tb1,
                                               const float* __restrict__ Tb2,
                                               const float* __restrict__ TW3,
                                               const float* __restrict__ Tb3,
                                               const int* __restrict__ cnt,
                                               const int* __restrict__ lists,
                                               float* __restrict__ out) {
  __shared__ __bf16 t_lds[4][16 * 128];
  int d  = blockIdx.y;
  int nc = cnt[d];
  int base = blockIdx.x * 64;
  if (base >= nc) return;

  int tid  = threadIdx.x;
  int lane = tid & 63;
  int w    = tid >> 6;
  int row  = lane & 15;
  int kq   = lane >> 4;
  int slot = base + w * 16 + row;
  bool valid = slot < nc;
  int m0r = lists[d * B_SZ + (valid ? slot : 0)];

  bf16x8 a1[8];
#pragma unroll
  for (int kk = 0; kk < 8; ++kk)
    a1[kk] = *(const bf16x8*)(h2 + (long)m0r * D2 + kk * 32 + kq * 8);

  f32x4 acc1[8] = {};
#pragma unroll
  for (int kk = 0; kk < 8; ++kk) {
#pragma unroll
    for (int ni = 0; ni < 8; ++ni) {
      bf16x8 b = *(const bf16x8*)(TW1P +
          ((long)(d * 64 + ni * 8 + kk) * 64 + lane) * 8);
      acc1[ni] = MFMA(a1[kk], b, acc1[ni]);
    }
  }
#pragma unroll
  for (int ni = 0; ni < 8; ++ni) {
    float bv = Tb1[d * T1D + ni * 16 + row];
#pragma unroll
    for (int r = 0; r < 4; ++r) {
      float v = acc1[ni][r] + bv;
      v = v > 0.f ? v : 0.f;
      t_lds[w][(kq * 4 + r) * 128 + ni * 16 + row] = (__bf16)v;
    }
  }
  asm volatile("s_waitcnt lgkmcnt(0)" ::: "memory");

  bf16x8 a2[4];
#pragma unroll
  for (int kk = 0; kk < 4; ++kk)
    a2[kk] = *(const bf16x8*)(&t_lds[w][row * 128 + kk * 32 + kq * 8]);
  f32x4 acc2[4] = {};
#pragma unroll
  for (int kk = 0; kk < 4; ++kk) {
#pragma unroll
    for (int ni = 0; ni < 4; ++ni) {
      bf16x8 b = *(const bf16x8*)(TW2P +
          ((long)(d * 16 + ni * 4 + kk) * 64 + lane) * 8);
      acc2[ni] = MFMA(a2[kk], b, acc2[ni]);
    }
  }
  asm volatile("s_waitcnt lgkmcnt(0)" ::: "memory");
#pragma unroll
  for (int ni = 0; ni < 4; ++ni) {
    float bv = Tb2[d * T2D + ni * 16 + row];
#pragma unroll
    for (int r = 0; r < 4; ++r) {
      float v = acc2[ni][r] + bv;
      v = v > 0.f ? v : 0.f;
      t_lds[w][(kq * 4 + r) * 64 + ni * 16 + row] = (__bf16)v;
    }
  }
  asm volatile("s_waitcnt lgkmcnt(0)" ::: "memory");

  float s = 0.f;
#pragma unroll
  for (int j = 0; j < 16; ++j)
    s += (float)t_lds[w][row * 64 + kq * 16 + j] * TW3[d * T2D + kq * 16 + j];
  s += __shfl_xor(s, 16);
  s += __shfl_xor(s, 32);
  s += Tb3[d];
  if (valid && kq == 0)
    out[m0r] = 1.0f / (1.0f + expf(-s));
}

// ---------------------------------------------------------------------------
extern "C" void kernel_launch(void* const* d_in, const int* in_sizes, int n_in,
                              void* d_out, int out_size, void* d_ws, size_t ws_size,
                              hipStream_t stream) {
  const int*   fids = (const int*)d_in[0];
  const int*   dom  = (const int*)d_in[1];
  const float* emb  = (const float*)d_in[2];
  const float* W1   = (const float*)d_in[3];
  const float* b1   = (const float*)d_in[4];
  const float* W2   = (const float*)d_in[5];
  const float* b2   = (const float*)d_in[6];
  const float* TW1  = (const float*)d_in[7];
  const float* Tb1  = (const float*)d_in[8];
  const float* TW2  = (const float*)d_in[9];
  const float* Tb2  = (const float*)d_in[10];
  const float* TW3  = (const float*)d_in[11];
  const float* Tb3  = (const float*)d_in[12];
  float* out = (float*)d_out;

  char* ws = (char*)d_ws;
  __bf16* W1P   = (__bf16*)(ws);                 // 655360
  __bf16* W2P   = (__bf16*)(ws + 655360);        // 262144
  __bf16* TW1P  = (__bf16*)(ws + 917504);        // 262144
  __bf16* TW2P  = (__bf16*)(ws + 1179648);       // 65536
  __bf16* h2    = (__bf16*)(ws + 1245184);       // 8388608
  int*    lists = (int*)(ws + 9633792);          // 262144
  int*    cnt   = (int*)(ws + 9895936);          // 16

  k_prep<<<305, 256, 0, stream>>>(W1, W2, TW1, TW2, W1P, W2P, TW1P, TW2P, cnt);
  k_fused<<<256, 512, 0, stream>>>(fids, dom, emb, W1P, b1, W2P, b2, h2,
                                   cnt, lists);
  k_tower<<<dim3(80, NDOM), 256, 0, stream>>>(h2, TW1P, TW2P, Tb1, Tb2,
                                              TW3, Tb3, cnt, lists, out);
}